// Round 2
// baseline (201.836 us; speedup 1.0000x reference)
//
#include <hip/hip_runtime.h>
#include <hip/hip_bf16.h>

// ---------------------------------------------------------------------------
// HessianCompatibleMultiHeadAttention on MI355X (gfx950).
// Inputs fp32, output fp32. Internal bf16 MFMA.
// B=2, S=2048, D=1024, H=16, Dk=64.
//   cvt_all:      x, wq, wk, wv, wo  -> bf16
//   gemm_bt<128>: qkv = x_bf @ W^T   (z=0 Q pre-scaled by 0.125*log2e)
//   transpose_v:  V plane -> V^T [bh][64][2048]
//   attn5:        flash attention, 64q per wave, waves = 2 kv-streams x
//                 2 kv-slices; K/V frags read once per 2 q-groups (halved
//                 LDS traffic); in-register P via pk2bf + permlane32_swap.
//   gemm_bt<64>:  out = ab @ Wo^T + b_o  (fp32 out, 512 blocks)
// ---------------------------------------------------------------------------

typedef __bf16 bf16x8 __attribute__((ext_vector_type(8)));
typedef float f32x4 __attribute__((ext_vector_type(4)));
typedef float f32x16 __attribute__((ext_vector_type(16)));

__device__ __forceinline__ unsigned short f2bf(float f) {
  union { float f; unsigned int u; } c; c.f = f;
  unsigned int u = c.u;
  return (unsigned short)((u + 0x7FFFu + ((u >> 16) & 1u)) >> 16);
}

// pack two fp32 -> two bf16 (round-half-up) in 3 VALU ops
__device__ __forceinline__ unsigned int pk2bf(float a, float b) {
  union { float f; unsigned int u; } x, y;
  x.f = a; y.f = b;
  return __builtin_amdgcn_perm(y.u + 0x8000u, x.u + 0x8000u, 0x07060302u);
}

__device__ __forceinline__ bf16x8 ld_frag(const unsigned short* p) {
  union { uint4 u; bf16x8 b; } c;
  c.u = *(const uint4*)p;   // 16B aligned -> ds_read_b128
  return c.b;
}

__device__ __forceinline__ uint4 cvt8(const float* __restrict__ p) {
  float4 a = *(const float4*)p;
  float4 b = *(const float4*)(p + 4);
  union { uint4 u; unsigned short s[8]; } r;
  r.s[0] = f2bf(a.x); r.s[1] = f2bf(a.y); r.s[2] = f2bf(a.z); r.s[3] = f2bf(a.w);
  r.s[4] = f2bf(b.x); r.s[5] = f2bf(b.y); r.s[6] = f2bf(b.z); r.s[7] = f2bf(b.w);
  return r.u;
}

// async global->LDS, 16B per lane (lds dest = wave-uniform base + lane*16)
typedef __attribute__((address_space(1))) const unsigned int as1_u32;
typedef __attribute__((address_space(3))) unsigned int as3_u32;
__device__ __forceinline__ void async16(const unsigned short* g,
                                        unsigned short* l) {
  __builtin_amdgcn_global_load_lds(
      (as1_u32*)(unsigned long long)g,
      (as3_u32*)(unsigned int)(unsigned long long)l, 16, 0, 0);
}

// ---------------------------------------------------------------------------
// fp32 -> bf16 conversion (memory-bound). grid (2048, 5).
// ---------------------------------------------------------------------------
__global__ __launch_bounds__(256) void cvt_all(
    const float* __restrict__ s0, const float* __restrict__ s1,
    const float* __restrict__ s2, const float* __restrict__ s3,
    const float* __restrict__ s4,
    unsigned short* __restrict__ d0, unsigned short* __restrict__ d1,
    unsigned short* __restrict__ d2, unsigned short* __restrict__ d3,
    unsigned short* __restrict__ d4) {
  const float* srcs[5] = {s0, s1, s2, s3, s4};
  unsigned short* dsts[5] = {d0, d1, d2, d3, d4};
  const int ns[5] = {4194304, 1048576, 1048576, 1048576, 1048576};
  const int y = blockIdx.y;
  const int idx = (blockIdx.x * 256 + threadIdx.x) * 8;
  if (idx >= ns[y]) return;
  *(uint4*)(dsts[y] + idx) = cvt8(srcs[y] + idx);
}

// ---------------------------------------------------------------------------
// GEMM: C[m][n] = scl * sum_k A[m][k] W[n][k] (+ bias[n]); bf16 in, fp32 acc.
// N=1024, K=1024. BN=128, BK=32, 256 thr.
// BM=128: 4 waves 2x2 of 64x64 (qkv path, grid (8,32,3)).
// BM=64:  4 waves 1x4, wave = 64m x 32n (out path, grid (8,64,1)).
// Staging: global_load_lds w=16; unpadded LDS [row][32], k-chunk XOR swizzle.
// ---------------------------------------------------------------------------
template <int BM, bool OUT_F32>
__global__ __launch_bounds__(256) void gemm_bt(
    const unsigned short* __restrict__ A,
    const unsigned short* __restrict__ w0,
    const unsigned short* __restrict__ w1,
    const unsigned short* __restrict__ w2,
    const float* __restrict__ bias,
    void* __restrict__ outraw, float z0scale) {
  constexpr int NT = (BM == 128) ? 4 : 2;
  const int z = blockIdx.z;
  const unsigned short* W = (z == 0) ? w0 : ((z == 1) ? w1 : w2);
  const float scl = (z == 0) ? z0scale : 1.0f;

  __shared__ unsigned short a_lds[BM * 32];
  __shared__ unsigned short b_lds[128 * 32];

  const int tid = threadIdx.x;
  const int wave = tid >> 6, lane = tid & 63;
  const int quad = lane >> 4, l16 = lane & 15;
  const int wm = (BM == 128) ? (wave >> 1) * 64 : 0;
  const int wn = (BM == 128) ? (wave & 1) * 64 : wave * 32;
  const int bm = blockIdx.y * BM, bn = blockIdx.x * 128;

  const int rl = lane >> 2;   // 0..15
  const int kc = (lane & 3) ^ (rl & 3) ^ ((rl >> 2) & 3);
  const int arow = (BM == 128) ? (wave * 32 + rl) : (wave * 16 + rl);
  const unsigned short* ga = A + (size_t)(bm + arow) * 1024 + kc * 8;
  const unsigned short* gb = W + (size_t)(bn + wave * 32 + rl) * 1024 + kc * 8;
  unsigned short* la = &a_lds[((BM == 128) ? wave * 32 : wave * 16) * 32];
  unsigned short* lb = &b_lds[wave * 32 * 32];

  const int rsw8 = ((l16 & 3) ^ ((l16 >> 2) & 3)) * 8;

  f32x4 acc[4][NT] = {};

  for (int k0 = 0; k0 < 1024; k0 += 32) {
    async16(ga, la);
    if (BM == 128) async16(ga + 16 * 1024, la + 16 * 32);
    async16(gb, lb);
    async16(gb + 16 * 1024, lb + 16 * 32);
    ga += 32; gb += 32;
    __syncthreads();

    bf16x8 af[4], bfr[NT];
#pragma unroll
    for (int t = 0; t < 4; ++t)
      af[t] = ld_frag(&a_lds[(wm + t * 16 + l16) * 32 + ((quad * 8) ^ rsw8)]);
#pragma unroll
    for (int t = 0; t < NT; ++t)
      bfr[t] = ld_frag(&b_lds[(wn + t * 16 + l16) * 32 + ((quad * 8) ^ rsw8)]);
#pragma unroll
    for (int mt = 0; mt < 4; ++mt)
#pragma unroll
      for (int nt = 0; nt < NT; ++nt)
        acc[mt][nt] = __builtin_amdgcn_mfma_f32_16x16x32_bf16(
            af[mt], bfr[nt], acc[mt][nt], 0, 0, 0);
    __syncthreads();
  }

  // Epilogue: C/D layout col = lane&15, row = quad*4 + reg  [m89-verified]
#pragma unroll
  for (int nt = 0; nt < NT; ++nt) {
    const int n = bn + wn + nt * 16 + l16;
    const float bv = bias ? bias[n] : 0.0f;
#pragma unroll
    for (int mt = 0; mt < 4; ++mt)
#pragma unroll
      for (int r = 0; r < 4; ++r) {
        const int m = bm + wm + mt * 16 + quad * 4 + r;
        const float v = acc[mt][nt][r] * scl + bv;
        if (OUT_F32)
          ((float*)outraw)[(size_t)z * 4096 * 1024 + (size_t)m * 1024 + n] = v;
        else
          ((unsigned short*)outraw)[(size_t)z * 4096 * 1024 +
                                    (size_t)m * 1024 + n] = f2bf(v);
      }
  }
}

// ---------------------------------------------------------------------------
// V plane [4096][1024] -> V^T [32 bh][64 d][2048 s]. grid (32, 32).
// ---------------------------------------------------------------------------
__global__ __launch_bounds__(256) void transpose_v(
    const unsigned short* __restrict__ v, unsigned short* __restrict__ vt) {
  const int st0 = blockIdx.x * 64;
  const int bh = blockIdx.y, b = bh >> 4, h = bh & 15;
  __shared__ unsigned short t[64 * 72];
  const int tid = threadIdx.x;
#pragma unroll
  for (int it = 0; it < 2; ++it) {
    const int c = it * 256 + tid;
    const int row = c >> 3, c8 = (c & 7) * 8;
    *(uint4*)&t[row * 72 + c8] =
        *(const uint4*)(v + (size_t)(b * 2048 + st0 + row) * 1024 + h * 64 + c8);
  }
  __syncthreads();
#pragma unroll
  for (int it = 0; it < 2; ++it) {
    const int c = it * 256 + tid;
    const int drow = c >> 3, s8 = (c & 7) * 8;
    union { uint4 u; unsigned short e[8]; } o;
#pragma unroll
    for (int j = 0; j < 8; ++j) o.e[j] = t[(s8 + j) * 72 + drow];
    *(uint4*)(vt + ((size_t)bh * 64 + drow) * 2048 + st0 + s8) = o.u;
  }
}

// ---------------------------------------------------------------------------
// Flash attention, 64 q per WAVE, no-max exp2 softmax (Q pre-scaled by
// 0.125*log2e).
//
// Block: 256 thr = 4 waves = 2 kv-streams (ws) x 2 kv-slices (hh).
//   wave (ws,hh): q rows qt*64..+63 (2 q-groups of 32), kv slice =
//   ws*1024 + t*64 + hh*32 .. +31 over 16 tiles of 64 kv per stream.
// Key change vs attn4: each K A-frag / V B-frag LDS read feeds BOTH q-groups
// (2 MFMAs per read) -> LDS frag traffic and bank conflicts halved.
// MFMA 32x32x16, S^T form: lane (hi,l32) holds S^T col q=l32, rows
//   kv_local = (r&3)+8*(r>>2)+4*hi  [m74/m101 layout].
// P in registers: pk2bf pairs -> u[qg][g][p]; 2x v_permlane32_swap_b32 per
//   16-kv chunk assembles the PV A-frag. No P LDS round-trip.
// LDS: per stream K tile [64 kv][64 d] + V^T tile [64 d][64 kv], 64-short
//   rows, slot^(row&7) XOR swizzle, staged via global_load_lds w=16 with the
//   inverse swizzle pre-applied to the per-lane GLOBAL source address.
// Epilogue: 2-round LDS tree combines 4 per-wave partial (O,l); exp2 softmax
//   has no running max -> partials are additive. wave0 normalizes + stores.
// LDS 34 KB; VGPR ~160 (launch_bounds 256,3) -> 3 blocks/CU = 12 waves/CU.
// grid (32 qt, 32 bh) = 1024 blocks.
// ---------------------------------------------------------------------------
__global__ __launch_bounds__(256, 3) void attn5(
    const unsigned short* __restrict__ qkv,   // Q plane at 0, K plane at PL
    const unsigned short* __restrict__ vt_g,  // [32][64][2048]
    unsigned short* __restrict__ ab) {
  constexpr size_t PL = (size_t)4096 * 1024;
  const int qt = blockIdx.x, bh = blockIdx.y;
  const int b = bh >> 4, hd = bh & 15;

  __shared__ __align__(16) unsigned short kvs[2][2][64 * 64];  // [ws][K,V][.]
  __shared__ float sm_l[4][2][32];   // [wave][qg][q]
  __shared__ float sm_lt[2][32];     // summed l

  const int tid = threadIdx.x;
  const int wave = tid >> 6, lane = tid & 63;
  const int ws = wave >> 1, hh = wave & 1;
  const int hi = lane >> 5, l32 = lane & 31;
  const int row8 = lane >> 3;                  // 0..7 (staging row in chunk)
  const int sl = (lane & 7) ^ (row8 & 7);      // pre-swizzled source slot
  const int swz = (l32 & 7) * 8;               // read-side XOR (shorts)

  // Q fragments (B operand): lane holds Q[q = qg*32+l32][d = kc*16 + hi*8 + j]
  bf16x8 qf[2][4];
#pragma unroll
  for (int qg = 0; qg < 2; ++qg) {
    const unsigned short* qrow =
        qkv + (size_t)(b * 2048 + qt * 64 + qg * 32 + l32) * 1024 + hd * 64 +
        hi * 8;
#pragma unroll
    for (int kc = 0; kc < 4; ++kc) qf[qg][kc] = ld_frag(qrow + kc * 16);
  }

  // staging pointers: per-lane global (swizzled), wave-uniform LDS base.
  // wave (ws,hh) stages K rows [hh*32..+31] and V^T d-rows [hh*32..+31] of
  // stream ws's tile (4 x 1 KiB chunks each).
  const unsigned short* gK =
      qkv + PL + (size_t)(b * 2048 + ws * 1024 + hh * 32 + row8) * 1024 +
      hd * 64 + sl * 8;
  const unsigned short* gV =
      vt_g + (size_t)bh * 64 * 2048 + (size_t)(hh * 32 + row8) * 2048 +
      ws * 1024 + sl * 8;
  unsigned short* lK = &kvs[ws][0][hh * 4 * 512];
  unsigned short* lV = &kvs[ws][1][hh * 4 * 512];

  f32x16 o_acc[2][2] = {};   // [qg][nb]: rows q = qg*32+crow, col d = nb*32+l32
  float l_part[2] = {0.0f, 0.0f};

  const int krow = (hh * 32 + l32) * 64;  // wave's K-slice row for A-frags

  for (int t = 0; t < 16; ++t) {
    // ---- stage K,V tiles (64 kv) for this stream ----
#pragma unroll
    for (int c = 0; c < 4; ++c) {
      async16(gK + (size_t)c * 8 * 1024, lK + c * 512);
      async16(gV + (size_t)c * 8 * 2048, lV + c * 512);
    }
    gK += 64 * 1024;  // next 64 kv rows
    gV += 64;         // next 64 kv cols
    __syncthreads();

    // ---- QK^T: S^T[kv_slice][q], A-frag shared by both q-groups ----
    f32x16 st[2] = {};
    __builtin_amdgcn_s_setprio(1);
#pragma unroll
    for (int kc = 0; kc < 4; ++kc) {
      bf16x8 ak = ld_frag(&kvs[ws][0][krow + (((2 * kc + hi) * 8) ^ swz)]);
      st[0] = __builtin_amdgcn_mfma_f32_32x32x16_bf16(ak, qf[0][kc], st[0],
                                                      0, 0, 0);
      st[1] = __builtin_amdgcn_mfma_f32_32x32x16_bf16(ak, qf[1][kc], st[1],
                                                      0, 0, 0);
    }
    __builtin_amdgcn_s_setprio(0);

    // ---- softmax (no-max exp2) + pack P to bf16 pairs in registers ----
    unsigned int u[2][4][2];
#pragma unroll
    for (int qg = 0; qg < 2; ++qg) {
#pragma unroll
      for (int r = 0; r < 16; ++r) {
        const float p = __builtin_amdgcn_exp2f(st[qg][r]);
        st[qg][r] = p;
        l_part[qg] += p;
      }
#pragma unroll
      for (int g = 0; g < 4; ++g) {
        u[qg][g][0] = pk2bf(st[qg][g * 4 + 0], st[qg][g * 4 + 1]);
        u[qg][g][1] = pk2bf(st[qg][g * 4 + 2], st[qg][g * 4 + 3]);
      }
    }

    // ---- PV: O += P.V, V B-frags read once and shared by both q-groups ----
#pragma unroll
    for (int ks = 0; ks < 2; ++ks) {
      bf16x8 bv0 = ld_frag(
          &kvs[ws][1][(0 * 32 + l32) * 64 + (((hh * 4 + ks * 2 + hi) * 8) ^ swz)]);
      bf16x8 bv1 = ld_frag(
          &kvs[ws][1][(1 * 32 + l32) * 64 + (((hh * 4 + ks * 2 + hi) * 8) ^ swz)]);
#pragma unroll
      for (int qg = 0; qg < 2; ++qg) {
        unsigned int a0 = u[qg][2 * ks][0], b0 = u[qg][2 * ks + 1][0];
        unsigned int a1 = u[qg][2 * ks][1], b1 = u[qg][2 * ks + 1][1];
        // after swap: a' = [a.lo | b.lo], b' = [a.hi | b.hi]
        asm("v_permlane32_swap_b32 %0, %1" : "+v"(a0), "+v"(b0));
        asm("v_permlane32_swap_b32 %0, %1" : "+v"(a1), "+v"(b1));
        union { unsigned int w[4]; bf16x8 f; } pa;
        pa.w[0] = a0; pa.w[1] = a1; pa.w[2] = b0; pa.w[3] = b1;
        __builtin_amdgcn_s_setprio(1);
        o_acc[qg][0] = __builtin_amdgcn_mfma_f32_32x32x16_bf16(pa.f, bv0,
                                                               o_acc[qg][0],
                                                               0, 0, 0);
        o_acc[qg][1] = __builtin_amdgcn_mfma_f32_32x32x16_bf16(pa.f, bv1,
                                                               o_acc[qg][1],
                                                               0, 0, 0);
        __builtin_amdgcn_s_setprio(0);
      }
    }
    __syncthreads();  // all frag reads done -> restage safe
  }

  // ---- combine 4 per-wave partials: O = sum O_w / sum l_w ----
  // lanes hi=0/1 hold disjoint kv rows of the same q column -> reduce l
  float lsum[2];
#pragma unroll
  for (int qg = 0; qg < 2; ++qg)
    lsum[qg] = l_part[qg] + __shfl_xor(l_part[qg], 32);
  if (lane < 32) {
    sm_l[wave][0][l32] = lsum[0];
    sm_l[wave][1][l32] = lsum[1];
  }

  float* sm_o = (float*)&kvs[0][0][0];  // 2 x [64 q][64 d] fp32 = 32 KiB
  if (wave >= 2) {
#pragma unroll
    for (int qg = 0; qg < 2; ++qg)
#pragma unroll
      for (int nb = 0; nb < 2; ++nb)
#pragma unroll
        for (int r = 0; r < 16; ++r) {
          const int q = qg * 32 + (r & 3) + 8 * (r >> 2) + 4 * hi;
          sm_o[(wave - 2) * 4096 + q * 64 + nb * 32 + l32] = o_acc[qg][nb][r];
        }
  }
  __syncthreads();

  if (tid < 64) {
    const int qg = tid >> 5, qq = tid & 31;
    sm_lt[qg][qq] = sm_l[0][qg][qq] + sm_l[1][qg][qq] + sm_l[2][qg][qq] +
                    sm_l[3][qg][qq];
  }
  if (wave < 2) {
#pragma unroll
    for (int qg = 0; qg < 2; ++qg)
#pragma unroll
      for (int nb = 0; nb < 2; ++nb)
#pragma unroll
        for (int r = 0; r < 16; ++r) {
          const int q = qg * 32 + (r & 3) + 8 * (r >> 2) + 4 * hi;
          o_acc[qg][nb][r] += sm_o[wave * 4096 + q * 64 + nb * 32 + l32];
        }
  }
  __syncthreads();

  if (wave == 1) {
#pragma unroll
    for (int qg = 0; qg < 2; ++qg)
#pragma unroll
      for (int nb = 0; nb < 2; ++nb)
#pragma unroll
        for (int r = 0; r < 16; ++r) {
          const int q = qg * 32 + (r & 3) + 8 * (r >> 2) + 4 * hi;
          sm_o[q * 64 + nb * 32 + l32] = o_acc[qg][nb][r];
        }
  }
  __syncthreads();

  if (wave == 0) {
#pragma unroll
    for (int qg = 0; qg < 2; ++qg)
#pragma unroll
      for (int r = 0; r < 16; ++r) {
        const int crow = (r & 3) + 8 * (r >> 2) + 4 * hi;
        const int q = qg * 32 + crow;
        const float inv = __builtin_amdgcn_rcpf(sm_lt[qg][crow]);
        const size_t row = (size_t)(b * 2048 + qt * 64 + q);
#pragma unroll
        for (int nb = 0; nb < 2; ++nb) {
          const float v =
              (o_acc[qg][nb][r] + sm_o[q * 64 + nb * 32 + l32]) * inv;
          ab[row * 1024 + hd * 64 + nb * 32 + l32] = f2bf(v);
        }
      }
  }
}

// ---------------------------------------------------------------------------
extern "C" void kernel_launch(void* const* d_in, const int* in_sizes, int n_in,
                              void* d_out, int out_size, void* d_ws,
                              size_t ws_size, hipStream_t stream) {
  const float* x  = (const float*)d_in[0];
  const float* wq = (const float*)d_in[1];
  const float* wk = (const float*)d_in[2];
  const float* wv = (const float*)d_in[3];
  const float* wo = (const float*)d_in[4];
  const float* bo = (const float*)d_in[5];

  constexpr size_t PL = (size_t)4096 * 1024;
  unsigned short* qkv = (unsigned short*)d_ws;   // 3 planes: Q, K, V
  unsigned short* ab  = qkv + 2 * PL;            // overlays dead V plane
  unsigned short* xb  = qkv + 3 * PL;            // x bf16; later vt alias
  unsigned short* vt  = xb;                      // V^T [32][64][2048]
  unsigned short* wqb = qkv + 4 * PL;
  unsigned short* wkb = wqb + 1024 * 1024;
  unsigned short* wvb = wkb + 1024 * 1024;
  unsigned short* wob = wvb + 1024 * 1024;

  const float QSCALE = 0.18033688011112042f;  // 0.125 * log2(e)

  cvt_all<<<dim3(2048, 5), 256, 0, stream>>>(x, wq, wk, wv, wo,
                                             xb, wqb, wkb, wvb, wob);
  gemm_bt<128, false><<<dim3(8, 32, 3), 256, 0, stream>>>(
      xb, wqb, wkb, wvb, nullptr, qkv, QSCALE);
  transpose_v<<<dim3(32, 32), 256, 0, stream>>>(qkv + 2 * PL, vt);
  attn5<<<dim3(32, 32), 256, 0, stream>>>(qkv, vt, ab);
  gemm_bt<64, true><<<dim3(8, 64, 1), 256, 0, stream>>>(
      ab, wob, wob, wob, bo, d_out, 1.0f);
}

// Round 3
// 196.562 us; speedup vs baseline: 1.0268x; 1.0268x over previous
//
#include <hip/hip_runtime.h>
#include <hip/hip_bf16.h>

// ---------------------------------------------------------------------------
// HessianCompatibleMultiHeadAttention on MI355X (gfx950).
// Inputs fp32, output fp32. Internal bf16 MFMA.
// B=2, S=2048, D=1024, H=16, Dk=64.
//   cvt_all:      x, wq, wk, wv, wo  -> bf16
//   gemm_bt<128>: qkv = x_bf @ W^T   (z=0 Q pre-scaled by 0.125*log2e)
//                 2-phase double-buffered LDS prefetch (T3-min recipe)
//   transpose_v:  V plane -> V^T [bh][64][2048]
//   attn4:        flash attention, q-tile 64, in-block kv-split (2 streams),
//                 32x32x16 MFMA, in-register P (pk2bf + v_permlane32_swap),
//                 XOR-swizzled K/V LDS tiles staged via global_load_lds.
//                 [verified 53.4 us — do not touch]
//   gemm_bt<64>:  out = ab @ Wo^T + b_o  (fp32 out, 512 blocks)
// ---------------------------------------------------------------------------

typedef __bf16 bf16x8 __attribute__((ext_vector_type(8)));
typedef float f32x4 __attribute__((ext_vector_type(4)));
typedef float f32x16 __attribute__((ext_vector_type(16)));

__device__ __forceinline__ unsigned short f2bf(float f) {
  union { float f; unsigned int u; } c; c.f = f;
  unsigned int u = c.u;
  return (unsigned short)((u + 0x7FFFu + ((u >> 16) & 1u)) >> 16);
}

// pack two fp32 -> two bf16 (round-half-up) in 3 VALU ops
__device__ __forceinline__ unsigned int pk2bf(float a, float b) {
  union { float f; unsigned int u; } x, y;
  x.f = a; y.f = b;
  return __builtin_amdgcn_perm(y.u + 0x8000u, x.u + 0x8000u, 0x07060302u);
}

__device__ __forceinline__ bf16x8 ld_frag(const unsigned short* p) {
  union { uint4 u; bf16x8 b; } c;
  c.u = *(const uint4*)p;   // 16B aligned -> ds_read_b128
  return c.b;
}

__device__ __forceinline__ uint4 cvt8(const float* __restrict__ p) {
  float4 a = *(const float4*)p;
  float4 b = *(const float4*)(p + 4);
  union { uint4 u; unsigned short s[8]; } r;
  r.s[0] = f2bf(a.x); r.s[1] = f2bf(a.y); r.s[2] = f2bf(a.z); r.s[3] = f2bf(a.w);
  r.s[4] = f2bf(b.x); r.s[5] = f2bf(b.y); r.s[6] = f2bf(b.z); r.s[7] = f2bf(b.w);
  return r.u;
}

// async global->LDS, 16B per lane (lds dest = wave-uniform base + lane*16)
typedef __attribute__((address_space(1))) const unsigned int as1_u32;
typedef __attribute__((address_space(3))) unsigned int as3_u32;
__device__ __forceinline__ void async16(const unsigned short* g,
                                        unsigned short* l) {
  __builtin_amdgcn_global_load_lds(
      (as1_u32*)(unsigned long long)g,
      (as3_u32*)(unsigned int)(unsigned long long)l, 16, 0, 0);
}

// ---------------------------------------------------------------------------
// fp32 -> bf16 conversion (memory-bound). grid (2048, 5).
// ---------------------------------------------------------------------------
__global__ __launch_bounds__(256) void cvt_all(
    const float* __restrict__ s0, const float* __restrict__ s1,
    const float* __restrict__ s2, const float* __restrict__ s3,
    const float* __restrict__ s4,
    unsigned short* __restrict__ d0, unsigned short* __restrict__ d1,
    unsigned short* __restrict__ d2, unsigned short* __restrict__ d3,
    unsigned short* __restrict__ d4) {
  const float* srcs[5] = {s0, s1, s2, s3, s4};
  unsigned short* dsts[5] = {d0, d1, d2, d3, d4};
  const int ns[5] = {4194304, 1048576, 1048576, 1048576, 1048576};
  const int y = blockIdx.y;
  const int idx = (blockIdx.x * 256 + threadIdx.x) * 8;
  if (idx >= ns[y]) return;
  *(uint4*)(dsts[y] + idx) = cvt8(srcs[y] + idx);
}

// ---------------------------------------------------------------------------
// GEMM: C[m][n] = scl * sum_k A[m][k] W[n][k] (+ bias[n]); bf16 in, fp32 acc.
// N=1024, K=1024. BN=128, BK=32, 256 thr.
// BM=128: 4 waves 2x2 of 64x64 (qkv path, grid (8,32,3)).
// BM=64:  4 waves 1x4, wave = 64m x 32n (out path, grid (8,64,1)).
// Staging: global_load_lds w=16; unpadded LDS [row][32], k-chunk XOR swizzle.
// 2-PHASE: double-buffered LDS; issue next K-tile's global_load_lds BEFORE
// current tile's ds_read+MFMA; ONE barrier per K-step (T3-min, m248 recipe).
// ---------------------------------------------------------------------------
template <int BM, bool OUT_F32>
__global__ __launch_bounds__(256) void gemm_bt(
    const unsigned short* __restrict__ A,
    const unsigned short* __restrict__ w0,
    const unsigned short* __restrict__ w1,
    const unsigned short* __restrict__ w2,
    const float* __restrict__ bias,
    void* __restrict__ outraw, float z0scale) {
  constexpr int NT = (BM == 128) ? 4 : 2;
  const int z = blockIdx.z;
  const unsigned short* W = (z == 0) ? w0 : ((z == 1) ? w1 : w2);
  const float scl = (z == 0) ? z0scale : 1.0f;

  __shared__ unsigned short a_lds[2][BM * 32];
  __shared__ unsigned short b_lds[2][128 * 32];

  const int tid = threadIdx.x;
  const int wave = tid >> 6, lane = tid & 63;
  const int quad = lane >> 4, l16 = lane & 15;
  const int wm = (BM == 128) ? (wave >> 1) * 64 : 0;
  const int wn = (BM == 128) ? (wave & 1) * 64 : wave * 32;
  const int bm = blockIdx.y * BM, bn = blockIdx.x * 128;

  const int rl = lane >> 2;   // 0..15
  const int kc = (lane & 3) ^ (rl & 3) ^ ((rl >> 2) & 3);
  const int arow = (BM == 128) ? (wave * 32 + rl) : (wave * 16 + rl);
  const unsigned short* ga = A + (size_t)(bm + arow) * 1024 + kc * 8;
  const unsigned short* gb = W + (size_t)(bn + wave * 32 + rl) * 1024 + kc * 8;
  const int abase = ((BM == 128) ? wave * 32 : wave * 16) * 32;
  const int bbase = wave * 32 * 32;

  const int rsw8 = ((l16 & 3) ^ ((l16 >> 2) & 3)) * 8;

  f32x4 acc[4][NT] = {};

  // prologue: stage K-tile 0 into buffer 0
  async16(ga, &a_lds[0][abase]);
  if (BM == 128) async16(ga + 16 * 1024, &a_lds[0][abase + 16 * 32]);
  async16(gb, &b_lds[0][bbase]);
  async16(gb + 16 * 1024, &b_lds[0][bbase + 16 * 32]);
  ga += 32; gb += 32;
  __syncthreads();  // implicit vmcnt(0) drain -> buf0 ready

  int cur = 0;
#pragma unroll 2
  for (int k0 = 0; k0 < 1024; k0 += 32) {
    // ---- prefetch next K-tile into the other buffer (overlaps compute) ----
    if (k0 < 992) {
      const int nxt = cur ^ 1;
      async16(ga, &a_lds[nxt][abase]);
      if (BM == 128) async16(ga + 16 * 1024, &a_lds[nxt][abase + 16 * 32]);
      async16(gb, &b_lds[nxt][bbase]);
      async16(gb + 16 * 1024, &b_lds[nxt][bbase + 16 * 32]);
      ga += 32; gb += 32;
    }

    // ---- compute current buffer ----
    bf16x8 af[4], bfr[NT];
#pragma unroll
    for (int t = 0; t < 4; ++t)
      af[t] =
          ld_frag(&a_lds[cur][(wm + t * 16 + l16) * 32 + ((quad * 8) ^ rsw8)]);
#pragma unroll
    for (int t = 0; t < NT; ++t)
      bfr[t] =
          ld_frag(&b_lds[cur][(wn + t * 16 + l16) * 32 + ((quad * 8) ^ rsw8)]);
#pragma unroll
    for (int mt = 0; mt < 4; ++mt)
#pragma unroll
      for (int nt = 0; nt < NT; ++nt)
        acc[mt][nt] = __builtin_amdgcn_mfma_f32_16x16x32_bf16(
            af[mt], bfr[nt], acc[mt][nt], 0, 0, 0);

    __syncthreads();  // drains prefetch (in flight during compute) + read done
    cur ^= 1;
  }

  // Epilogue: C/D layout col = lane&15, row = quad*4 + reg  [m89-verified]
#pragma unroll
  for (int nt = 0; nt < NT; ++nt) {
    const int n = bn + wn + nt * 16 + l16;
    const float bv = bias ? bias[n] : 0.0f;
#pragma unroll
    for (int mt = 0; mt < 4; ++mt)
#pragma unroll
      for (int r = 0; r < 4; ++r) {
        const int m = bm + wm + mt * 16 + quad * 4 + r;
        const float v = acc[mt][nt][r] * scl + bv;
        if (OUT_F32)
          ((float*)outraw)[(size_t)z * 4096 * 1024 + (size_t)m * 1024 + n] = v;
        else
          ((unsigned short*)outraw)[(size_t)z * 4096 * 1024 +
                                    (size_t)m * 1024 + n] = f2bf(v);
      }
  }
}

// ---------------------------------------------------------------------------
// V plane [4096][1024] -> V^T [32 bh][64 d][2048 s]. grid (32, 32).
// ---------------------------------------------------------------------------
__global__ __launch_bounds__(256) void transpose_v(
    const unsigned short* __restrict__ v, unsigned short* __restrict__ vt) {
  const int st0 = blockIdx.x * 64;
  const int bh = blockIdx.y, b = bh >> 4, h = bh & 15;
  __shared__ unsigned short t[64 * 72];
  const int tid = threadIdx.x;
#pragma unroll
  for (int it = 0; it < 2; ++it) {
    const int c = it * 256 + tid;
    const int row = c >> 3, c8 = (c & 7) * 8;
    *(uint4*)&t[row * 72 + c8] =
        *(const uint4*)(v + (size_t)(b * 2048 + st0 + row) * 1024 + h * 64 + c8);
  }
  __syncthreads();
#pragma unroll
  for (int it = 0; it < 2; ++it) {
    const int c = it * 256 + tid;
    const int drow = c >> 3, s8 = (c & 7) * 8;
    union { uint4 u; unsigned short e[8]; } o;
#pragma unroll
    for (int j = 0; j < 8; ++j) o.e[j] = t[(s8 + j) * 72 + drow];
    *(uint4*)(vt + ((size_t)bh * 64 + drow) * 2048 + st0 + s8) = o.u;
  }
}

// ---------------------------------------------------------------------------
// Flash attention, q-tile 64, in-block kv-split, no-max exp2 softmax
// (Q pre-scaled by 0.125*log2e).  [verified 53.4 us @ round 1 — unchanged]
//
// Block: 256 thr = 4 waves = 2 q-groups (wq) x 2 kv-streams (ws).
//   wave (wq,ws): 32 q rows = qt*64 + wq*32, kv range = ws*1024 .. +1023,
//   iterated in 16 tiles of KVBLK=64.
// MFMA 32x32x16, S^T form (A = K rows, B = Q cols): lane (hi,l32) holds
//   S^T col q=l32, rows kv = 32mb + 4hi + (r&3) + 8(r>>2)  [m74/m101 layout].
// P stays IN REGISTERS: pk2bf pairs -> u[mb][g][p] (kv = 32mb+4hi+8g+2p+{0,1});
//   2x v_permlane32_swap_b32 per k-chunk assembles the PV A-frag
//   (lane needs P[q][16ks+8hi+j]) -- no P LDS round-trip, no P barrier.
// LDS: per stream K tile [64 kv][64 d] + V^T tile [64 d][64 kv], 64-short rows
//   with slot^(row&7) XOR swizzle; staged by global_load_lds w=16 with the
//   inverse swizzle pre-applied to the per-lane GLOBAL source address
//   (LDS dest stays linear). Conflict-free ds_read_b128 frag reads.
// Epilogue: streams combine unnormalized O (fp32) + l through LDS (exp2
//   softmax has no running max -> partials are additive), normalize, store.
// LDS 33280 B, VGPR <=128 (launch_bounds 256,4) -> 4 blocks/CU = 16 waves/CU.
// grid (32 qt, 32 bh) = 1024 blocks.
// ---------------------------------------------------------------------------
__global__ __launch_bounds__(256, 4) void attn4(
    const unsigned short* __restrict__ qkv,   // Q plane at 0, K plane at PL
    const unsigned short* __restrict__ vt_g,  // [32][64][2048]
    unsigned short* __restrict__ ab) {
  constexpr size_t PL = (size_t)4096 * 1024;
  const int qt = blockIdx.x, bh = blockIdx.y;
  const int b = bh >> 4, h = bh & 15;

  __shared__ __align__(16) unsigned short kvs[2][2][64 * 64];  // [ws][K,V][.]
  __shared__ float sm_l[2][2][32];                             // [ws][wq][q]

  const int tid = threadIdx.x;
  const int wave = tid >> 6, lane = tid & 63;
  const int ws = wave >> 1, wq = wave & 1;
  const int hi = lane >> 5, l32 = lane & 31;
  const int row8 = lane >> 3;                  // 0..7 (staging row in chunk)
  const int sl = (lane & 7) ^ (row8 & 7);      // pre-swizzled source slot
  const int swz = (l32 & 7) * 8;               // read-side XOR (shorts)

  // Q fragments (B operand): lane holds Q[q=l32][d = kc*16 + hi*8 + j]
  const unsigned short* qrow =
      qkv + (size_t)(b * 2048 + qt * 64 + wq * 32 + l32) * 1024 + h * 64 +
      hi * 8;
  bf16x8 qf[4];
#pragma unroll
  for (int kc = 0; kc < 4; ++kc) qf[kc] = ld_frag(qrow + kc * 16);

  // staging pointers: per-lane global (swizzled), wave-uniform LDS base.
  // wave wq stages chunks wq*4..wq*4+3 (1 KiB each) of its stream's K and V.
  const unsigned short* gK =
      qkv + PL + (size_t)(b * 2048 + ws * 1024 + wq * 32 + row8) * 1024 +
      h * 64 + sl * 8;
  const unsigned short* gV =
      vt_g + (size_t)bh * 64 * 2048 + (size_t)(wq * 32 + row8) * 2048 +
      ws * 1024 + sl * 8;
  unsigned short* lK = &kvs[ws][0][wq * 4 * 512];
  unsigned short* lV = &kvs[ws][1][wq * 4 * 512];

  f32x16 o_acc[2] = {};
  float l_part = 0.0f;

  for (int t = 0; t < 16; ++t) {
    // ---- stage K,V tiles (64 kv) for this stream ----
#pragma unroll
    for (int c = 0; c < 4; ++c) {
      async16(gK + (size_t)c * 8 * 1024, lK + c * 512);
      async16(gV + (size_t)c * 8 * 2048, lV + c * 512);
    }
    gK += 64 * 1024;  // next 64 kv rows
    gV += 64;         // next 64 kv cols
    __syncthreads();

    // ---- QK^T: S^T[kv][q], 2 mb x 4 kc ----
    f32x16 st[2] = {};
#pragma unroll
    for (int mb = 0; mb < 2; ++mb)
#pragma unroll
      for (int kc = 0; kc < 4; ++kc) {
        bf16x8 ak = ld_frag(
            &kvs[ws][0][(mb * 32 + l32) * 64 + (((2 * kc + hi) * 8) ^ swz)]);
        st[mb] = __builtin_amdgcn_mfma_f32_32x32x16_bf16(ak, qf[kc], st[mb],
                                                         0, 0, 0);
      }

    // ---- softmax (no-max exp2) + pack P to bf16 pairs in registers ----
    unsigned int u[2][4][2];
#pragma unroll
    for (int mb = 0; mb < 2; ++mb) {
#pragma unroll
      for (int r = 0; r < 16; ++r) {
        const float p = __builtin_amdgcn_exp2f(st[mb][r]);
        st[mb][r] = p;
        l_part += p;
      }
#pragma unroll
      for (int g = 0; g < 4; ++g) {
        u[mb][g][0] = pk2bf(st[mb][g * 4 + 0], st[mb][g * 4 + 1]);
        u[mb][g][1] = pk2bf(st[mb][g * 4 + 2], st[mb][g * 4 + 3]);
      }
    }

    // ---- PV: O += P.V, A-frags assembled via permlane32_swap ----
#pragma unroll
    for (int ks = 0; ks < 4; ++ks) {
      const int m = ks >> 1, g = (ks & 1) * 2;
      unsigned int a0 = u[m][g][0], b0 = u[m][g + 1][0];
      unsigned int a1 = u[m][g][1], b1 = u[m][g + 1][1];
      // after swap: a' = [a.lo | b.lo], b' = [a.hi | b.hi]
      asm("v_permlane32_swap_b32 %0, %1" : "+v"(a0), "+v"(b0));
      asm("v_permlane32_swap_b32 %0, %1" : "+v"(a1), "+v"(b1));
      union { unsigned int w[4]; bf16x8 f; } pa;
      pa.w[0] = a0; pa.w[1] = a1; pa.w[2] = b0; pa.w[3] = b1;
#pragma unroll
      for (int nb = 0; nb < 2; ++nb) {
        bf16x8 bv = ld_frag(
            &kvs[ws][1][(nb * 32 + l32) * 64 + (((2 * ks + hi) * 8) ^ swz)]);
        o_acc[nb] = __builtin_amdgcn_mfma_f32_32x32x16_bf16(pa.f, bv,
                                                            o_acc[nb], 0, 0, 0);
      }
    }
    __syncthreads();  // all frag reads done -> restage safe
  }

  // ---- cross-stream combine: O = (O0+O1) / (l0+l1) ----
  float lsum = l_part + __shfl_xor(l_part, 32);  // full kv-half sum, q=l32

  float* sm_o = (float*)&kvs[0][0][0];  // [2 wq][32 q][64 d] fp32 = 16 KiB
  if (ws == 1) {
#pragma unroll
    for (int nb = 0; nb < 2; ++nb)
#pragma unroll
      for (int r = 0; r < 16; ++r) {
        const int q = (r & 3) + 8 * (r >> 2) + 4 * hi;
        sm_o[wq * 2048 + q * 64 + nb * 32 + l32] = o_acc[nb][r];
      }
  }
  if (lane < 32) sm_l[ws][wq][l32] = lsum;
  __syncthreads();

  if (ws == 0) {
#pragma unroll
    for (int r = 0; r < 16; ++r) {
      const int q = (r & 3) + 8 * (r >> 2) + 4 * hi;
      const float inv = 1.0f / (sm_l[0][wq][q] + sm_l[1][wq][q]);
      const size_t row = (size_t)(b * 2048 + qt * 64 + wq * 32 + q);
#pragma unroll
      for (int nb = 0; nb < 2; ++nb) {
        const float v =
            (o_acc[nb][r] + sm_o[wq * 2048 + q * 64 + nb * 32 + l32]) * inv;
        ab[row * 1024 + h * 64 + nb * 32 + l32] = f2bf(v);
      }
    }
  }
}

// ---------------------------------------------------------------------------
extern "C" void kernel_launch(void* const* d_in, const int* in_sizes, int n_in,
                              void* d_out, int out_size, void* d_ws,
                              size_t ws_size, hipStream_t stream) {
  const float* x  = (const float*)d_in[0];
  const float* wq = (const float*)d_in[1];
  const float* wk = (const float*)d_in[2];
  const float* wv = (const float*)d_in[3];
  const float* wo = (const float*)d_in[4];
  const float* bo = (const float*)d_in[5];

  constexpr size_t PL = (size_t)4096 * 1024;
  unsigned short* qkv = (unsigned short*)d_ws;   // 3 planes: Q, K, V
  unsigned short* ab  = qkv + 2 * PL;            // overlays dead V plane
  unsigned short* xb  = qkv + 3 * PL;            // x bf16; later vt alias
  unsigned short* vt  = xb;                      // V^T [32][64][2048]
  unsigned short* wqb = qkv + 4 * PL;
  unsigned short* wkb = wqb + 1024 * 1024;
  unsigned short* wvb = wkb + 1024 * 1024;
  unsigned short* wob = wvb + 1024 * 1024;

  const float QSCALE = 0.18033688011112042f;  // 0.125 * log2(e)

  cvt_all<<<dim3(2048, 5), 256, 0, stream>>>(x, wq, wk, wv, wo,
                                             xb, wqb, wkb, wvb, wob);
  gemm_bt<128, false><<<dim3(8, 32, 3), 256, 0, stream>>>(
      xb, wqb, wkb, wvb, nullptr, qkv, QSCALE);
  transpose_v<<<dim3(32, 32), 256, 0, stream>>>(qkv + 2 * PL, vt);
  attn4<<<dim3(32, 32), 256, 0, stream>>>(qkv, vt, ab);
  gemm_bt<64, true><<<dim3(8, 64, 1), 256, 0, stream>>>(
      ab, wob, wob, wob, bo, d_out, 1.0f);
}

// Round 4
// 181.268 us; speedup vs baseline: 1.1135x; 1.0844x over previous
//
#include <hip/hip_runtime.h>
#include <hip/hip_bf16.h>

// ---------------------------------------------------------------------------
// HessianCompatibleMultiHeadAttention on MI355X (gfx950).
// Inputs fp32, output fp32. Internal bf16 MFMA.
// B=2, S=2048, D=1024, H=16, Dk=64.
//   cvt_all:      x, wq, wk, wv, wo  -> bf16
//   gemm_bt<128>: qkv = x_bf @ W^T   (z=0 Q pre-scaled by 0.125*log2e)
//                 BK=64 single-buffer (m97 recipe), XCD-local grid (x=m-tile)
//   transpose_v:  V plane -> V^T [bh][64][2048]
//   attn4:        flash attention, q-tile 64, in-block kv-split (2 streams),
//                 32x32x16 MFMA, in-register P (pk2bf + v_permlane32_swap),
//                 XOR-swizzled K/V LDS tiles staged via global_load_lds.
//                 [verified 52.2 us — do not touch]
//   gemm_bt<64>:  out = ab @ Wo^T + b_o  (fp32 out)
// ---------------------------------------------------------------------------

typedef __bf16 bf16x8 __attribute__((ext_vector_type(8)));
typedef float f32x4 __attribute__((ext_vector_type(4)));
typedef float f32x16 __attribute__((ext_vector_type(16)));

__device__ __forceinline__ unsigned short f2bf(float f) {
  union { float f; unsigned int u; } c; c.f = f;
  unsigned int u = c.u;
  return (unsigned short)((u + 0x7FFFu + ((u >> 16) & 1u)) >> 16);
}

// pack two fp32 -> two bf16 (round-half-up) in 3 VALU ops
__device__ __forceinline__ unsigned int pk2bf(float a, float b) {
  union { float f; unsigned int u; } x, y;
  x.f = a; y.f = b;
  return __builtin_amdgcn_perm(y.u + 0x8000u, x.u + 0x8000u, 0x07060302u);
}

__device__ __forceinline__ bf16x8 ld_frag(const unsigned short* p) {
  union { uint4 u; bf16x8 b; } c;
  c.u = *(const uint4*)p;   // 16B aligned -> ds_read_b128
  return c.b;
}

__device__ __forceinline__ uint4 cvt8(const float* __restrict__ p) {
  float4 a = *(const float4*)p;
  float4 b = *(const float4*)(p + 4);
  union { uint4 u; unsigned short s[8]; } r;
  r.s[0] = f2bf(a.x); r.s[1] = f2bf(a.y); r.s[2] = f2bf(a.z); r.s[3] = f2bf(a.w);
  r.s[4] = f2bf(b.x); r.s[5] = f2bf(b.y); r.s[6] = f2bf(b.z); r.s[7] = f2bf(b.w);
  return r.u;
}

// async global->LDS, 16B per lane (lds dest = wave-uniform base + lane*16)
typedef __attribute__((address_space(1))) const unsigned int as1_u32;
typedef __attribute__((address_space(3))) unsigned int as3_u32;
__device__ __forceinline__ void async16(const unsigned short* g,
                                        unsigned short* l) {
  __builtin_amdgcn_global_load_lds(
      (as1_u32*)(unsigned long long)g,
      (as3_u32*)(unsigned int)(unsigned long long)l, 16, 0, 0);
}

// ---------------------------------------------------------------------------
// fp32 -> bf16 conversion (memory-bound). grid (2048, 5).
// ---------------------------------------------------------------------------
__global__ __launch_bounds__(256) void cvt_all(
    const float* __restrict__ s0, const float* __restrict__ s1,
    const float* __restrict__ s2, const float* __restrict__ s3,
    const float* __restrict__ s4,
    unsigned short* __restrict__ d0, unsigned short* __restrict__ d1,
    unsigned short* __restrict__ d2, unsigned short* __restrict__ d3,
    unsigned short* __restrict__ d4) {
  const float* srcs[5] = {s0, s1, s2, s3, s4};
  unsigned short* dsts[5] = {d0, d1, d2, d3, d4};
  const int ns[5] = {4194304, 1048576, 1048576, 1048576, 1048576};
  const int y = blockIdx.y;
  const int idx = (blockIdx.x * 256 + threadIdx.x) * 8;
  if (idx >= ns[y]) return;
  *(uint4*)(dsts[y] + idx) = cvt8(srcs[y] + idx);
}

// ---------------------------------------------------------------------------
// GEMM: C[m][n] = scl * sum_k A[m][k] W[n][k] (+ bias[n]); bf16 in, fp32 acc.
// N=1024, K=1024. BN=128, BK=64 (m97 recipe), single-buffered, 256 thr.
// BM=128: 4 waves 2x2 of 64x64 (qkv path, grid (32,8,3), x = m-tile).
// BM=64:  4 waves 1x4, wave = 64m x 32n (out path, grid (64,8,1)).
// Grid: x = m-tile (fast dispatch dim) -> all 8 n-blocks sharing an A-panel
// land on ONE XCD (linear%8 = mx%8) -> A-panel fetched once into that L2.
// Staging: global_load_lds w=16, 8-row 1KiB chunks; LDS [row][64] with
// slot^(row&7) XOR swizzle pre-applied to the per-lane GLOBAL source
// address (LDS dest linear). Frag reads ds_read_b128, 2-way (free).
// ---------------------------------------------------------------------------
template <int BM, bool OUT_F32>
__global__ __launch_bounds__(256, 3) void gemm_bt(
    const unsigned short* __restrict__ A,
    const unsigned short* __restrict__ w0,
    const unsigned short* __restrict__ w1,
    const unsigned short* __restrict__ w2,
    const float* __restrict__ bias,
    void* __restrict__ outraw, float z0scale) {
  constexpr int NT = (BM == 128) ? 4 : 2;
  constexpr int RA = BM / 4;  // A rows staged per wave
  const int z = blockIdx.z;
  const unsigned short* W = (z == 0) ? w0 : ((z == 1) ? w1 : w2);
  const float scl = (z == 0) ? z0scale : 1.0f;

  __shared__ unsigned short a_lds[BM * 64];
  __shared__ unsigned short b_lds[128 * 64];

  const int tid = threadIdx.x;
  const int wave = tid >> 6, lane = tid & 63;
  const int quad = lane >> 4, l16 = lane & 15;
  const int wm = (BM == 128) ? (wave >> 1) * 64 : 0;
  const int wn = (BM == 128) ? (wave & 1) * 64 : wave * 32;
  const int bm = blockIdx.x * BM, bn = blockIdx.y * 128;

  // staging: 1 KiB chunk = 8 rows x 64 shorts; lane covers (row8, slot)
  const int r8 = lane >> 3;            // row within chunk (0..7)
  const int sl = (lane & 7) ^ r8;      // inverse-swizzled k-chunk (16B units)
  const unsigned short* ga = A + (size_t)(bm + wave * RA + r8) * 1024 + sl * 8;
  const unsigned short* gb = W + (size_t)(bn + wave * 32 + r8) * 1024 + sl * 8;
  unsigned short* la = &a_lds[wave * RA * 64];
  unsigned short* lb = &b_lds[wave * 32 * 64];

  f32x4 acc[4][NT] = {};

  for (int k0 = 0; k0 < 1024; k0 += 64) {
    // ---- stage A (RA rows/wave) and B (32 rows/wave) ----
#pragma unroll
    for (int c = 0; c < RA / 8; ++c)
      async16(ga + (size_t)c * 8 * 1024, la + c * 512);
#pragma unroll
    for (int c = 0; c < 4; ++c)
      async16(gb + (size_t)c * 8 * 1024, lb + c * 512);
    ga += 64; gb += 64;
    __syncthreads();

    // ---- frag reads: chunk (kk*4+quad) ^ (row&7), row-major [row][64] ----
    bf16x8 af[2][4], bfr[2][NT];
#pragma unroll
    for (int kk = 0; kk < 2; ++kk) {
#pragma unroll
      for (int t = 0; t < 4; ++t) {
        const int row = wm + t * 16 + l16;
        af[kk][t] =
            ld_frag(&a_lds[row * 64 + (((kk * 4 + quad) ^ (row & 7)) * 8)]);
      }
#pragma unroll
      for (int t = 0; t < NT; ++t) {
        const int row = wn + t * 16 + l16;
        bfr[kk][t] =
            ld_frag(&b_lds[row * 64 + (((kk * 4 + quad) ^ (row & 7)) * 8)]);
      }
    }
#pragma unroll
    for (int kk = 0; kk < 2; ++kk)
#pragma unroll
      for (int mt = 0; mt < 4; ++mt)
#pragma unroll
        for (int nt = 0; nt < NT; ++nt)
          acc[mt][nt] = __builtin_amdgcn_mfma_f32_16x16x32_bf16(
              af[kk][mt], bfr[kk][nt], acc[mt][nt], 0, 0, 0);
    __syncthreads();
  }

  // Epilogue: C/D layout col = lane&15, row = quad*4 + reg  [m89-verified]
#pragma unroll
  for (int nt = 0; nt < NT; ++nt) {
    const int n = bn + wn + nt * 16 + l16;
    const float bv = bias ? bias[n] : 0.0f;
#pragma unroll
    for (int mt = 0; mt < 4; ++mt)
#pragma unroll
      for (int r = 0; r < 4; ++r) {
        const int m = bm + wm + mt * 16 + quad * 4 + r;
        const float v = acc[mt][nt][r] * scl + bv;
        if (OUT_F32)
          ((float*)outraw)[(size_t)z * 4096 * 1024 + (size_t)m * 1024 + n] = v;
        else
          ((unsigned short*)outraw)[(size_t)z * 4096 * 1024 +
                                    (size_t)m * 1024 + n] = f2bf(v);
      }
  }
}

// ---------------------------------------------------------------------------
// V plane [4096][1024] -> V^T [32 bh][64 d][2048 s]. grid (32, 32).
// ---------------------------------------------------------------------------
__global__ __launch_bounds__(256) void transpose_v(
    const unsigned short* __restrict__ v, unsigned short* __restrict__ vt) {
  const int st0 = blockIdx.x * 64;
  const int bh = blockIdx.y, b = bh >> 4, h = bh & 15;
  __shared__ unsigned short t[64 * 72];
  const int tid = threadIdx.x;
#pragma unroll
  for (int it = 0; it < 2; ++it) {
    const int c = it * 256 + tid;
    const int row = c >> 3, c8 = (c & 7) * 8;
    *(uint4*)&t[row * 72 + c8] =
        *(const uint4*)(v + (size_t)(b * 2048 + st0 + row) * 1024 + h * 64 + c8);
  }
  __syncthreads();
#pragma unroll
  for (int it = 0; it < 2; ++it) {
    const int c = it * 256 + tid;
    const int drow = c >> 3, s8 = (c & 7) * 8;
    union { uint4 u; unsigned short e[8]; } o;
#pragma unroll
    for (int j = 0; j < 8; ++j) o.e[j] = t[(s8 + j) * 72 + drow];
    *(uint4*)(vt + ((size_t)bh * 64 + drow) * 2048 + st0 + s8) = o.u;
  }
}

// ---------------------------------------------------------------------------
// Flash attention, q-tile 64, in-block kv-split, no-max exp2 softmax
// (Q pre-scaled by 0.125*log2e).  [verified 52.2 us @ round 3 — unchanged]
//
// Block: 256 thr = 4 waves = 2 q-groups (wq) x 2 kv-streams (ws).
//   wave (wq,ws): 32 q rows = qt*64 + wq*32, kv range = ws*1024 .. +1023,
//   iterated in 16 tiles of KVBLK=64.
// MFMA 32x32x16, S^T form (A = K rows, B = Q cols): lane (hi,l32) holds
//   S^T col q=l32, rows kv = 32mb + 4hi + (r&3) + 8(r>>2)  [m74/m101 layout].
// P stays IN REGISTERS: pk2bf pairs -> u[mb][g][p] (kv = 32mb+4hi+8g+2p+{0,1});
//   2x v_permlane32_swap_b32 per k-chunk assembles the PV A-frag
//   (lane needs P[q][16ks+8hi+j]) -- no P LDS round-trip, no P barrier.
// LDS: per stream K tile [64 kv][64 d] + V^T tile [64 d][64 kv], 64-short rows
//   with slot^(row&7) XOR swizzle; staged by global_load_lds w=16 with the
//   inverse swizzle pre-applied to the per-lane GLOBAL source address
//   (LDS dest stays linear). Conflict-free ds_read_b128 frag reads.
// Epilogue: streams combine unnormalized O (fp32) + l through LDS (exp2
//   softmax has no running max -> partials are additive), normalize, store.
// LDS 33280 B, VGPR <=128 (launch_bounds 256,4) -> 4 blocks/CU = 16 waves/CU.
// grid (32 qt, 32 bh) = 1024 blocks.
// ---------------------------------------------------------------------------
__global__ __launch_bounds__(256, 4) void attn4(
    const unsigned short* __restrict__ qkv,   // Q plane at 0, K plane at PL
    const unsigned short* __restrict__ vt_g,  // [32][64][2048]
    unsigned short* __restrict__ ab) {
  constexpr size_t PL = (size_t)4096 * 1024;
  const int qt = blockIdx.x, bh = blockIdx.y;
  const int b = bh >> 4, h = bh & 15;

  __shared__ __align__(16) unsigned short kvs[2][2][64 * 64];  // [ws][K,V][.]
  __shared__ float sm_l[2][2][32];                             // [ws][wq][q]

  const int tid = threadIdx.x;
  const int wave = tid >> 6, lane = tid & 63;
  const int ws = wave >> 1, wq = wave & 1;
  const int hi = lane >> 5, l32 = lane & 31;
  const int row8 = lane >> 3;                  // 0..7 (staging row in chunk)
  const int sl = (lane & 7) ^ (row8 & 7);      // pre-swizzled source slot
  const int swz = (l32 & 7) * 8;               // read-side XOR (shorts)

  // Q fragments (B operand): lane holds Q[q=l32][d = kc*16 + hi*8 + j]
  const unsigned short* qrow =
      qkv + (size_t)(b * 2048 + qt * 64 + wq * 32 + l32) * 1024 + h * 64 +
      hi * 8;
  bf16x8 qf[4];
#pragma unroll
  for (int kc = 0; kc < 4; ++kc) qf[kc] = ld_frag(qrow + kc * 16);

  // staging pointers: per-lane global (swizzled), wave-uniform LDS base.
  // wave wq stages chunks wq*4..wq*4+3 (1 KiB each) of its stream's K and V.
  const unsigned short* gK =
      qkv + PL + (size_t)(b * 2048 + ws * 1024 + wq * 32 + row8) * 1024 +
      h * 64 + sl * 8;
  const unsigned short* gV =
      vt_g + (size_t)bh * 64 * 2048 + (size_t)(wq * 32 + row8) * 2048 +
      ws * 1024 + sl * 8;
  unsigned short* lK = &kvs[ws][0][wq * 4 * 512];
  unsigned short* lV = &kvs[ws][1][wq * 4 * 512];

  f32x16 o_acc[2] = {};
  float l_part = 0.0f;

  for (int t = 0; t < 16; ++t) {
    // ---- stage K,V tiles (64 kv) for this stream ----
#pragma unroll
    for (int c = 0; c < 4; ++c) {
      async16(gK + (size_t)c * 8 * 1024, lK + c * 512);
      async16(gV + (size_t)c * 8 * 2048, lV + c * 512);
    }
    gK += 64 * 1024;  // next 64 kv rows
    gV += 64;         // next 64 kv cols
    __syncthreads();

    // ---- QK^T: S^T[kv][q], 2 mb x 4 kc ----
    f32x16 st[2] = {};
#pragma unroll
    for (int mb = 0; mb < 2; ++mb)
#pragma unroll
      for (int kc = 0; kc < 4; ++kc) {
        bf16x8 ak = ld_frag(
            &kvs[ws][0][(mb * 32 + l32) * 64 + (((2 * kc + hi) * 8) ^ swz)]);
        st[mb] = __builtin_amdgcn_mfma_f32_32x32x16_bf16(ak, qf[kc], st[mb],
                                                         0, 0, 0);
      }

    // ---- softmax (no-max exp2) + pack P to bf16 pairs in registers ----
    unsigned int u[2][4][2];
#pragma unroll
    for (int mb = 0; mb < 2; ++mb) {
#pragma unroll
      for (int r = 0; r < 16; ++r) {
        const float p = __builtin_amdgcn_exp2f(st[mb][r]);
        st[mb][r] = p;
        l_part += p;
      }
#pragma unroll
      for (int g = 0; g < 4; ++g) {
        u[mb][g][0] = pk2bf(st[mb][g * 4 + 0], st[mb][g * 4 + 1]);
        u[mb][g][1] = pk2bf(st[mb][g * 4 + 2], st[mb][g * 4 + 3]);
      }
    }

    // ---- PV: O += P.V, A-frags assembled via permlane32_swap ----
#pragma unroll
    for (int ks = 0; ks < 4; ++ks) {
      const int m = ks >> 1, g = (ks & 1) * 2;
      unsigned int a0 = u[m][g][0], b0 = u[m][g + 1][0];
      unsigned int a1 = u[m][g][1], b1 = u[m][g + 1][1];
      // after swap: a' = [a.lo | b.lo], b' = [a.hi | b.hi]
      asm("v_permlane32_swap_b32 %0, %1" : "+v"(a0), "+v"(b0));
      asm("v_permlane32_swap_b32 %0, %1" : "+v"(a1), "+v"(b1));
      union { unsigned int w[4]; bf16x8 f; } pa;
      pa.w[0] = a0; pa.w[1] = a1; pa.w[2] = b0; pa.w[3] = b1;
#pragma unroll
      for (int nb = 0; nb < 2; ++nb) {
        bf16x8 bv = ld_frag(
            &kvs[ws][1][(nb * 32 + l32) * 64 + (((2 * ks + hi) * 8) ^ swz)]);
        o_acc[nb] = __builtin_amdgcn_mfma_f32_32x32x16_bf16(pa.f, bv,
                                                            o_acc[nb], 0, 0, 0);
      }
    }
    __syncthreads();  // all frag reads done -> restage safe
  }

  // ---- cross-stream combine: O = (O0+O1) / (l0+l1) ----
  float lsum = l_part + __shfl_xor(l_part, 32);  // full kv-half sum, q=l32

  float* sm_o = (float*)&kvs[0][0][0];  // [2 wq][32 q][64 d] fp32 = 16 KiB
  if (ws == 1) {
#pragma unroll
    for (int nb = 0; nb < 2; ++nb)
#pragma unroll
      for (int r = 0; r < 16; ++r) {
        const int q = (r & 3) + 8 * (r >> 2) + 4 * hi;
        sm_o[wq * 2048 + q * 64 + nb * 32 + l32] = o_acc[nb][r];
      }
  }
  if (lane < 32) sm_l[ws][wq][l32] = lsum;
  __syncthreads();

  if (ws == 0) {
#pragma unroll
    for (int r = 0; r < 16; ++r) {
      const int q = (r & 3) + 8 * (r >> 2) + 4 * hi;
      const float inv = 1.0f / (sm_l[0][wq][q] + sm_l[1][wq][q]);
      const size_t row = (size_t)(b * 2048 + qt * 64 + wq * 32 + q);
#pragma unroll
      for (int nb = 0; nb < 2; ++nb) {
        const float v =
            (o_acc[nb][r] + sm_o[wq * 2048 + q * 64 + nb * 32 + l32]) * inv;
        ab[row * 1024 + h * 64 + nb * 32 + l32] = f2bf(v);
      }
    }
  }
}

// ---------------------------------------------------------------------------
extern "C" void kernel_launch(void* const* d_in, const int* in_sizes, int n_in,
                              void* d_out, int out_size, void* d_ws,
                              size_t ws_size, hipStream_t stream) {
  const float* x  = (const float*)d_in[0];
  const float* wq = (const float*)d_in[1];
  const float* wk = (const float*)d_in[2];
  const float* wv = (const float*)d_in[3];
  const float* wo = (const float*)d_in[4];
  const float* bo = (const float*)d_in[5];

  constexpr size_t PL = (size_t)4096 * 1024;
  unsigned short* qkv = (unsigned short*)d_ws;   // 3 planes: Q, K, V
  unsigned short* ab  = qkv + 2 * PL;            // overlays dead V plane
  unsigned short* xb  = qkv + 3 * PL;            // x bf16; later vt alias
  unsigned short* vt  = xb;                      // V^T [32][64][2048]
  unsigned short* wqb = qkv + 4 * PL;
  unsigned short* wkb = wqb + 1024 * 1024;
  unsigned short* wvb = wkb + 1024 * 1024;
  unsigned short* wob = wvb + 1024 * 1024;

  const float QSCALE = 0.18033688011112042f;  // 0.125 * log2(e)

  cvt_all<<<dim3(2048, 5), 256, 0, stream>>>(x, wq, wk, wv, wo,
                                             xb, wqb, wkb, wvb, wob);
  gemm_bt<128, false><<<dim3(32, 8, 3), 256, 0, stream>>>(
      xb, wqb, wkb, wvb, nullptr, qkv, QSCALE);
  transpose_v<<<dim3(32, 32), 256, 0, stream>>>(qkv + 2 * PL, vt);
  attn4<<<dim3(32, 32), 256, 0, stream>>>(qkv, vt, ab);
  gemm_bt<64, true><<<dim3(64, 8, 1), 256, 0, stream>>>(
      ab, wob, wob, wob, bo, d_out, 1.0f);
}